// Round 8
// baseline (193.265 us; speedup 1.0000x reference)
//
#include <hip/hip_runtime.h>

#define OUT 7
#define NCH 256
#define NROI 512
#define NS 14            // bilinear samples per axis (7 bins x 2)
#define NT 28            // tap slots per axis (lo/hi per sample)
#define CCH 16           // channels per block
#define W9 9             // LDS words per row-slot within a col-slot: 8 cp + 1 pad
#define WPC 253          // LDS words per col-slot: 28*9 + 1 (odd -> conflict-free)
#define TPR (NCH * OUT * OUT)

__device__ __forceinline__ float rfl_f(float v) {
    return __int_as_float(__builtin_amdgcn_readfirstlane(__float_as_int(v)));
}

// 8B load with only 4B alignment guarantee (col pair may start at odd col).
__device__ __forceinline__ float2 ld2(const float* p) {
    float2 r;
    __builtin_memcpy(&r, p, sizeof(float2));
    return r;
}

// D[15:0]=bf16(lo), D[31:16]=bf16(hi), RNE — matches the original manual round.
__device__ __forceinline__ unsigned int cvt_pk_bf16(float lo, float hi) {
    unsigned int r;
    asm("v_cvt_pk_bf16_f32 %0, %1, %2" : "=v"(r) : "v"(lo), "v"(hi));
    return r;
}

// ---------------------------------------------------------------------------
// Pre-pass: sort RoIs by (image, level, y-band, x-band) so that each XCD's
// contiguous run of 64 sorted RoIs has overlapping feature footprints ->
// shared plane regions stay resident in the XCD's 4MB L2 (kernel is
// beyond-L2-traffic-bound: time tracked bytes at ~2.8 TB/s across R0-R7).
// Bitonic sort of 512 packed keys in LDS; perm written to workspace.
// Output is indexed by the true RoI id, so any permutation is bit-identical.
// ---------------------------------------------------------------------------
__global__ __launch_bounds__(NROI) void roi_sort_kernel(
        const float* __restrict__ boxes, int* __restrict__ perm) {
    __shared__ unsigned int keys[NROI];
    int i = (int)threadIdx.x;

    float bx1 = boxes[i * 4 + 0], by1 = boxes[i * 4 + 1];
    float bx2 = boxes[i * 4 + 2], by2 = boxes[i * 4 + 3];
    float area = (bx2 - bx1) * (by2 - by1);
    float s    = sqrtf(area);
    float lvl  = floorf(4.0f + log2f(s * (1.0f / 224.0f) + 1e-6f));
    lvl        = fminf(fmaxf(lvl, 2.0f), 5.0f);
    int level  = (int)lvl - 2;

    float scale, Hf;
    switch (level) {
        case 0:  Hf = 200.0f; scale = 0.25f;    break;
        case 1:  Hf = 100.0f; scale = 0.125f;   break;
        case 2:  Hf = 50.0f;  scale = 0.0625f;  break;
        default: Hf = 25.0f;  scale = 0.03125f; break;
    }
    float xn = 0.5f * (bx1 + bx2) * scale / Hf;   // normalized center
    float yn = 0.5f * (by1 + by2) * scale / Hf;
    int kx = (int)(xn * 8.0f); kx = kx < 0 ? 0 : (kx > 7 ? 7 : kx);
    int ky = (int)(yn * 8.0f); ky = ky < 0 ? 0 : (ky > 7 ? 7 : ky);
    int img = i >> 8;

    keys[i] = ((unsigned)img << 17) | ((unsigned)level << 15) |
              ((unsigned)ky << 12)  | ((unsigned)kx << 9) | (unsigned)i;

    for (unsigned k = 2; k <= NROI; k <<= 1) {
        for (unsigned j = k >> 1; j > 0; j >>= 1) {
            __syncthreads();
            unsigned ixj = (unsigned)i ^ j;
            if (ixj > (unsigned)i) {
                unsigned a = keys[i], b = keys[ixj];
                bool up = ((i & k) == 0);
                if ((a > b) == up) { keys[i] = b; keys[ixj] = a; }
            }
        }
    }
    __syncthreads();
    perm[i] = (int)(keys[i] & 511u);
}

// Block = (sorted-RoI slot, 16-channel chunk). Main kernel is the verified
// 65us tap-gather structure (R3), with r taken through the locality
// permutation: XCD x processes sorted RoIs [64x, 64x+64), all 16 chunks of
// a sorted RoI consecutive. Loads issue first (per-lane addresses from the
// wave-uniform box), weight LUT overlaps them. Phase 3: 49 px x 8
// channel-pairs pooled from LDS. Phase 4: repack + float4 store.
// LDS word index: colslot*253 + rowslot*9 + cp  (cp = channel pair 0..7).
__global__ __launch_bounds__(256, 4) void roi_align_tap16_kernel(
        const float* __restrict__ f0, const float* __restrict__ f1,
        const float* __restrict__ f2, const float* __restrict__ f3,
        const float* __restrict__ boxes, const int* __restrict__ perm,
        float* __restrict__ out) {
    __shared__ __align__(16) unsigned short sm[NT * WPC * 2];  // 28,336 B
    __shared__ float lyS[NS], vyS[NS], lxS[NS], vxS[NS];

    int bid  = blockIdx.x;
    int xcd  = bid & 7;
    int k    = bid >> 3;
    int sidx = xcd * 64 + (k >> 4);     // sorted slot: contiguous run per XCD
    int q    = k & 15;                  // 16-channel chunk
    int r    = __builtin_amdgcn_readfirstlane(perm[sidx]);   // true RoI id
    int tid  = (int)threadIdx.x;

    // ---------------- wave-uniform RoI meta ----------------
    float bx1 = rfl_f(boxes[r * 4 + 0]);
    float by1 = rfl_f(boxes[r * 4 + 1]);
    float bx2 = rfl_f(boxes[r * 4 + 2]);
    float by2 = rfl_f(boxes[r * 4 + 3]);

    float area = (bx2 - bx1) * (by2 - by1);
    float s    = sqrtf(area);
    float lvl  = floorf(4.0f + log2f(s * (1.0f / 224.0f) + 1e-6f));
    lvl        = fminf(fmaxf(lvl, 2.0f), 5.0f);
    int level  = __builtin_amdgcn_readfirstlane((int)lvl - 2);

    const float* f; int H; float scale;
    switch (level) {
        case 0:  f = f0; H = 200; scale = 0.25f;    break;
        case 1:  f = f1; H = 100; scale = 0.125f;   break;
        case 2:  f = f2; H = 50;  scale = 0.0625f;  break;
        default: f = f3; H = 25;  scale = 0.03125f; break;
    }
    float Hf = (float)H;

    float x1 = bx1 * scale, y1 = by1 * scale;
    float roi_w = fmaxf(bx2 * scale - x1, 1.0f);
    float roi_h = fmaxf(by2 * scale - y1, 1.0f);
    float bin_w = roi_w * (1.0f / OUT);
    float bin_h = roi_h * (1.0f / OUT);

    // ---------------- phase 2a: per-lane tap addresses + ISSUE all loads ----
    int bidx = r >> 8;   // 256 RoIs per batch image
    size_t HH = (size_t)(H * H);
    const float* plane = f + (size_t)(bidx * NCH + q * CCH) * HH;

    int lane = tid & 63;
    int wave = tid >> 6;
    int cq   = lane / 14;  if (cq > 3) cq = 3;         // channel quad 0..3
    int sp   = lane - cq * 14;  if (sp > 13) sp = 13;  // x sample 0..13
    bool act = lane < 56;

    // col pair for this lane's x sample (bitwise-identical to weight-LUT math)
    int pw = sp >> 1, ixs = sp & 1;
    float xs = x1 + ((float)pw + (ixs ? 0.75f : 0.25f)) * bin_w;
    xs = fmaxf(xs, 0.0f);
    int xl = (int)xs;
    int c0; bool sel;
    if (xl >= H - 1) { c0 = H - 2; sel = true; }   // clamped: both taps = f[H-1]
    else             { c0 = xl;    sel = false; }

    // rows for this wave's 7 row-slots (slot rs -> y sample rs>>1, lo/hi rs&1)
    int roff[7];
#pragma unroll
    for (int t = 0; t < 7; ++t) {
        int rs = wave * 7 + t;
        int sy = rs >> 1;
        int ph = sy >> 1, iy = sy & 1;
        float ys = y1 + ((float)ph + (iy ? 0.75f : 0.25f)) * bin_h;
        ys = fmaxf(ys, 0.0f);
        int yl = (int)ys;
        int row = (yl >= H - 1) ? (H - 1) : (yl + (rs & 1));
        roff[t] = row * H + c0;
    }

    const float* base = plane + (size_t)(cq * 4) * HH;   // ch 4cq..4cq+3

    // issue all 28 col-pair loads before the convert region
    float2 v[7][4];
#pragma unroll
    for (int t = 0; t < 7; ++t)
#pragma unroll
        for (int cc = 0; cc < 4; ++cc)
            v[t][cc] = ld2(base + (size_t)cc * HH + (size_t)roff[t]);
    asm volatile("" ::: "memory");
    __builtin_amdgcn_sched_barrier(0);

    // ---------------- phase 1 (overlapped): weight LUT ----------------
    if (tid < NS) {                       // y samples
        int ph = tid >> 1, iy = tid & 1;
        float y = y1 + ((float)ph + (iy ? 0.75f : 0.25f)) * bin_h;
        float vv = (y >= -1.0f && y <= Hf) ? 0.5f : 0.0f;   // vy*vx = 0.25
        y = fmaxf(y, 0.0f);
        int yl = (int)y;
        float ly = (yl >= H - 1) ? 0.0f : (y - (float)yl);
        lyS[tid] = ly; vyS[tid] = vv;
    } else if (tid >= 32 && tid < 32 + NS) {   // x samples
        int t = tid - 32;
        int pw2 = t >> 1, ix2 = t & 1;
        float x = x1 + ((float)pw2 + (ix2 ? 0.75f : 0.25f)) * bin_w;
        float vv = (x >= -1.0f && x <= Hf) ? 0.5f : 0.0f;
        x = fmaxf(x, 0.0f);
        int xl2 = (int)x;
        float lx = (xl2 >= H - 1) ? 0.0f : (x - (float)xl2);
        lxS[t] = lx; vxS[t] = vv;
    }

    // ---------------- phase 2b: convert + stage into LDS ----------------
    unsigned int* smw_w = (unsigned int*)sm;
    int wbase = (2 * sp) * WPC + 2 * cq;
#pragma unroll
    for (int t = 0; t < 7; ++t) {
        int rs = wave * 7 + t;                     // row slot 0..27
        // lo tap value: clamped cols read (H-2,H-1) and both taps = f[H-1]
        float l0 = sel ? v[t][0].y : v[t][0].x;
        float l1 = sel ? v[t][1].y : v[t][1].x;
        float l2 = sel ? v[t][2].y : v[t][2].x;
        float l3 = sel ? v[t][3].y : v[t][3].x;
        unsigned int lo01 = cvt_pk_bf16(l0, l1);
        unsigned int lo23 = cvt_pk_bf16(l2, l3);
        unsigned int hi01 = cvt_pk_bf16(v[t][0].y, v[t][1].y);
        unsigned int hi23 = cvt_pk_bf16(v[t][2].y, v[t][3].y);
        if (act) {
            unsigned int* d0 = smw_w + wbase + rs * W9;
            d0[0]       = lo01;   // colslot 2sp,   cp 2cq
            d0[1]       = lo23;   // colslot 2sp,   cp 2cq+1
            d0[WPC]     = hi01;   // colslot 2sp+1, cp 2cq
            d0[WPC + 1] = hi23;   // colslot 2sp+1, cp 2cq+1
        }
    }
    __syncthreads();

    // ---------------- phase 3: pool 49 px x 8 channel-pairs ----------------
    const unsigned int* smw = (const unsigned int*)sm;
    float accx[2], accy[2];
#pragma unroll
    for (int i = 0; i < 2; ++i) { accx[i] = 0.0f; accy[i] = 0.0f; }

#pragma unroll
    for (int i = 0; i < 2; ++i) {
        int o = tid + 256 * i;
        if (o < 392) {
            int cp = o & 7, px = o >> 3;
            int ph = px / 7, pw2 = px - ph * 7;
            float ax = 0.0f, ay = 0.0f;
#pragma unroll
            for (int iy = 0; iy < 2; ++iy) {
                int sy = ph * 2 + iy;
                float ly = lyS[sy], hy = 1.0f - ly;
                float vy = vyS[sy];
                int r0 = (2 * sy) * W9 + cp;
                int r1 = r0 + W9;
#pragma unroll
                for (int ix = 0; ix < 2; ++ix) {
                    int sx = pw2 * 2 + ix;
                    float lx = lxS[sx], hx = 1.0f - lx;
                    float m  = vy * vxS[sx];       // 0.25 if valid else 0
                    int c0i = (2 * sx) * WPC;
                    int c1i = c0i + WPC;
                    unsigned int u00 = smw[c0i + r0];
                    unsigned int u01 = smw[c1i + r0];
                    unsigned int u10 = smw[c0i + r1];
                    unsigned int u11 = smw[c1i + r1];
                    float w00 = hy * hx * m, w01 = hy * lx * m;
                    float w10 = ly * hx * m, w11 = ly * lx * m;
                    ax = fmaf(w00, __uint_as_float(u00 << 16), ax);
                    ay = fmaf(w00, __uint_as_float(u00 & 0xFFFF0000u), ay);
                    ax = fmaf(w01, __uint_as_float(u01 << 16), ax);
                    ay = fmaf(w01, __uint_as_float(u01 & 0xFFFF0000u), ay);
                    ax = fmaf(w10, __uint_as_float(u10 << 16), ax);
                    ay = fmaf(w10, __uint_as_float(u10 & 0xFFFF0000u), ay);
                    ax = fmaf(w11, __uint_as_float(u11 << 16), ax);
                    ay = fmaf(w11, __uint_as_float(u11 & 0xFFFF0000u), ay);
                }
            }
            accx[i] = ax; accy[i] = ay;
        }
    }
    __syncthreads();   // LDS reads done; reuse sm for output repack

    // ---------------- phase 4: repack via LDS, contiguous float4 store ----------------
    float* smf = (float*)sm;
#pragma unroll
    for (int i = 0; i < 2; ++i) {
        int o = tid + 256 * i;
        if (o < 392) {
            int cp = o & 7, px = o >> 3;
            smf[(cp * 2 + 0) * 49 + px] = accx[i];  // even channel (low ushort)
            smf[(cp * 2 + 1) * 49 + px] = accy[i];  // odd channel (high ushort)
        }
    }
    __syncthreads();

    float* dst = out + (size_t)r * TPR + (size_t)q * (CCH * 49);
    if (tid < 196)
        ((float4*)dst)[tid] = ((const float4*)smf)[tid];
}

extern "C" void kernel_launch(void* const* d_in, const int* in_sizes, int n_in,
                              void* d_out, int out_size, void* d_ws, size_t ws_size,
                              hipStream_t stream) {
    const float* f0    = (const float*)d_in[0];
    const float* f1    = (const float*)d_in[1];
    const float* f2    = (const float*)d_in[2];
    const float* f3    = (const float*)d_in[3];
    const float* boxes = (const float*)d_in[4];
    float* out         = (float*)d_out;
    int*   perm        = (int*)d_ws;

    roi_sort_kernel<<<1, NROI, 0, stream>>>(boxes, perm);
    roi_align_tap16_kernel<<<NROI * 16, 256, 0, stream>>>(f0, f1, f2, f3, boxes,
                                                          perm, out);
}

// Round 9
// 179.036 us; speedup vs baseline: 1.0795x; 1.0795x over previous
//
#include <hip/hip_runtime.h>

#define OUT 7
#define NCH 256
#define NROI 512
#define NS 14            // bilinear samples per axis (7 bins x 2)
#define NT 28            // tap slots per axis (lo/hi per sample)
#define CCH 8            // channels per block (16 -> 8: halves LDS, doubles blocks/CU)
#define W5 5             // LDS words per row-slot within a col-slot: 4 cp + 1 pad
#define WPC5 141         // LDS words per col-slot: 28*5 + 1 (odd -> conflict-free)
#define TPR (NCH * OUT * OUT)

__device__ __forceinline__ float rfl_f(float v) {
    return __int_as_float(__builtin_amdgcn_readfirstlane(__float_as_int(v)));
}

// D[15:0]=bf16(lo), D[31:16]=bf16(hi), RNE — matches the original manual round.
__device__ __forceinline__ unsigned int cvt_pk_bf16(float lo, float hi) {
    unsigned int r;
    asm("v_cvt_pk_bf16_f32 %0, %1, %2" : "=v"(r) : "v"(lo), "v"(hi));
    return r;
}

// Block = (RoI, 8-channel chunk) — the R3 tap-gather structure at HALF the
// LDS: 15.8 KB -> 8 blocks/CU (32 waves, HW cap) vs 4-5 before. All rounds
// so far were latency-bound at ~16-20 waves/CU (R8: bytes -3.3x, time WORSE;
// R1: VALU -30%, flat; MLP-deepening impossible at the RA's 44-VGPR policy);
// doubling resident waves is the one lever never varied.
// Per lane: 28 dword gathers (colslot j x 4 ch of its cg half); total
// line-requests conserved vs CCH=16 (each instr touches half the lines).
// Phase 3: 49 px x 4 channel-pairs pooled from LDS. Phase 4: float4 store.
// LDS word index: colslot*141 + rowslot*5 + cp  (cp = channel pair 0..3).
__global__ __launch_bounds__(256, 8) void roi_align_tap8_kernel(
        const float* __restrict__ f0, const float* __restrict__ f1,
        const float* __restrict__ f2, const float* __restrict__ f3,
        const float* __restrict__ boxes, float* __restrict__ out) {
    __shared__ __align__(16) unsigned int sm32[NT * WPC5];   // 15,792 B
    __shared__ float lyS[NS], vyS[NS], lxS[NS], vxS[NS];

    int g    = blockIdx.x;
    int xcd  = g & 7;
    int slot = g >> 3;
    int rr   = slot >> 5;
    int q    = slot & 31;          // 8-channel chunk 0..31
    int r    = rr * 8 + xcd;       // RoI id: all 32 chunks share g%8 (same XCD)
    int tid  = (int)threadIdx.x;

    // ---------------- wave-uniform RoI meta ----------------
    float bx1 = rfl_f(boxes[r * 4 + 0]);
    float by1 = rfl_f(boxes[r * 4 + 1]);
    float bx2 = rfl_f(boxes[r * 4 + 2]);
    float by2 = rfl_f(boxes[r * 4 + 3]);

    float area = (bx2 - bx1) * (by2 - by1);
    float s    = sqrtf(area);
    float lvl  = floorf(4.0f + log2f(s * (1.0f / 224.0f) + 1e-6f));
    lvl        = fminf(fmaxf(lvl, 2.0f), 5.0f);
    int level  = __builtin_amdgcn_readfirstlane((int)lvl - 2);

    const float* f; int H; float scale;
    switch (level) {
        case 0:  f = f0; H = 200; scale = 0.25f;    break;
        case 1:  f = f1; H = 100; scale = 0.125f;   break;
        case 2:  f = f2; H = 50;  scale = 0.0625f;  break;
        default: f = f3; H = 25;  scale = 0.03125f; break;
    }
    float Hf = (float)H;

    float x1 = bx1 * scale, y1 = by1 * scale;
    float roi_w = fmaxf(bx2 * scale - x1, 1.0f);
    float roi_h = fmaxf(by2 * scale - y1, 1.0f);
    float bin_w = roi_w * (1.0f / OUT);
    float bin_h = roi_h * (1.0f / OUT);

    // ---------------- phase 2a: per-lane tap addresses + ISSUE all loads ----
    int bidx = r >> 8;   // 256 RoIs per batch image
    size_t HH = (size_t)(H * H);
    const float* plane = f + (size_t)(bidx * NCH + q * CCH) * HH;

    int lane = tid & 63;
    int wave = tid >> 6;
    // lanes 0..27: colslot j, cg=0 (ch 0..3); lanes 28..55: colslot j, cg=1
    int  j   = (lane < 28) ? lane : ((lane < 56) ? lane - 28 : lane - 56);
    int  cg  = (lane >= 28 && lane < 56) ? 1 : 0;
    bool act = (lane < 56);

    // column for this lane's col-SLOT (slot j -> sample j>>1, lo/hi j&1)
    int sp = j >> 1, side = j & 1;
    int pw = sp >> 1, ixs = sp & 1;
    float xs = x1 + ((float)pw + (ixs ? 0.75f : 0.25f)) * bin_w;
    xs = fmaxf(xs, 0.0f);
    int xl = (int)xs;
    int col = (xl >= H - 1) ? (H - 1) : (xl + side);

    // rows for this wave's 7 row-slots (slot rs -> y sample rs>>1, lo/hi rs&1)
    int roff[7];
#pragma unroll
    for (int t = 0; t < 7; ++t) {
        int rs = wave * 7 + t;
        int sy = rs >> 1;
        int ph = sy >> 1, iy = sy & 1;
        float ys = y1 + ((float)ph + (iy ? 0.75f : 0.25f)) * bin_h;
        ys = fmaxf(ys, 0.0f);
        int yl = (int)ys;
        int row = (yl >= H - 1) ? (H - 1) : (yl + (rs & 1));
        roff[t] = row * H + col;
    }

    const float* base = plane + (size_t)(cg * 4) * HH;   // ch 4cg..4cg+3

    // issue all 28 tap loads (7 rows x 4 channels) before the convert region
    float v[7][4];
#pragma unroll
    for (int t = 0; t < 7; ++t)
#pragma unroll
        for (int cc = 0; cc < 4; ++cc)
            v[t][cc] = base[(size_t)cc * HH + (size_t)roff[t]];
    asm volatile("" ::: "memory");
    __builtin_amdgcn_sched_barrier(0);

    // ---------------- phase 1 (overlapped): weight LUT ----------------
    if (tid < NS) {                       // y samples
        int ph = tid >> 1, iy = tid & 1;
        float y = y1 + ((float)ph + (iy ? 0.75f : 0.25f)) * bin_h;
        float vv = (y >= -1.0f && y <= Hf) ? 0.5f : 0.0f;   // vy*vx = 0.25
        y = fmaxf(y, 0.0f);
        int yl = (int)y;
        float ly = (yl >= H - 1) ? 0.0f : (y - (float)yl);
        lyS[tid] = ly; vyS[tid] = vv;
    } else if (tid >= 32 && tid < 32 + NS) {   // x samples
        int t = tid - 32;
        int pw2 = t >> 1, ix2 = t & 1;
        float x = x1 + ((float)pw2 + (ix2 ? 0.75f : 0.25f)) * bin_w;
        float vv = (x >= -1.0f && x <= Hf) ? 0.5f : 0.0f;
        x = fmaxf(x, 0.0f);
        int xl2 = (int)x;
        float lx = (xl2 >= H - 1) ? 0.0f : (x - (float)xl2);
        lxS[t] = lx; vxS[t] = vv;
    }

    // ---------------- phase 2b: convert + stage into LDS ----------------
#pragma unroll
    for (int t = 0; t < 7; ++t) {
        int rs = wave * 7 + t;                     // row slot 0..27
        unsigned int w01 = cvt_pk_bf16(v[t][0], v[t][1]);
        unsigned int w23 = cvt_pk_bf16(v[t][2], v[t][3]);
        if (act) {
            unsigned int* d0 = sm32 + j * WPC5 + rs * W5 + 2 * cg;
            d0[0] = w01;   // cp 2cg   (ch 4cg, 4cg+1)
            d0[1] = w23;   // cp 2cg+1 (ch 4cg+2, 4cg+3)
        }
    }
    __syncthreads();

    // ---------------- phase 3: pool 49 px x 4 channel-pairs ----------------
    float accx = 0.0f, accy = 0.0f;
    int o = tid;
    if (o < 196) {
        int cp = o & 3, px = o >> 2;
        int ph = px / 7, pw2 = px - ph * 7;
        float ax = 0.0f, ay = 0.0f;
#pragma unroll
        for (int iy = 0; iy < 2; ++iy) {
            int sy = ph * 2 + iy;
            float ly = lyS[sy], hy = 1.0f - ly;
            float vy = vyS[sy];
            int r0 = (2 * sy) * W5 + cp;
            int r1 = r0 + W5;
#pragma unroll
            for (int ix = 0; ix < 2; ++ix) {
                int sx = pw2 * 2 + ix;
                float lx = lxS[sx], hx = 1.0f - lx;
                float m  = vy * vxS[sx];       // 0.25 if valid else 0
                int c0i = (2 * sx) * WPC5;
                int c1i = c0i + WPC5;
                unsigned int u00 = sm32[c0i + r0];
                unsigned int u01 = sm32[c1i + r0];
                unsigned int u10 = sm32[c0i + r1];
                unsigned int u11 = sm32[c1i + r1];
                float w00 = hy * hx * m, w01 = hy * lx * m;
                float w10 = ly * hx * m, w11 = ly * lx * m;
                ax = fmaf(w00, __uint_as_float(u00 << 16), ax);
                ay = fmaf(w00, __uint_as_float(u00 & 0xFFFF0000u), ay);
                ax = fmaf(w01, __uint_as_float(u01 << 16), ax);
                ay = fmaf(w01, __uint_as_float(u01 & 0xFFFF0000u), ay);
                ax = fmaf(w10, __uint_as_float(u10 << 16), ax);
                ay = fmaf(w10, __uint_as_float(u10 & 0xFFFF0000u), ay);
                ax = fmaf(w11, __uint_as_float(u11 << 16), ax);
                ay = fmaf(w11, __uint_as_float(u11 & 0xFFFF0000u), ay);
            }
        }
        accx = ax; accy = ay;
    }
    __syncthreads();   // LDS reads done; reuse sm32 for output repack

    // ---------------- phase 4: repack via LDS, contiguous float4 store -----
    float* smf = (float*)sm32;
    if (o < 196) {
        int cp = o & 3, px = o >> 2;
        smf[(cp * 2 + 0) * 49 + px] = accx;  // even channel (low ushort)
        smf[(cp * 2 + 1) * 49 + px] = accy;  // odd channel (high ushort)
    }
    __syncthreads();

    float* dst = out + (size_t)r * TPR + (size_t)q * (CCH * 49);
    if (tid < 98)
        ((float4*)dst)[tid] = ((const float4*)smf)[tid];
}

extern "C" void kernel_launch(void* const* d_in, const int* in_sizes, int n_in,
                              void* d_out, int out_size, void* d_ws, size_t ws_size,
                              hipStream_t stream) {
    const float* f0    = (const float*)d_in[0];
    const float* f1    = (const float*)d_in[1];
    const float* f2    = (const float*)d_in[2];
    const float* f3    = (const float*)d_in[3];
    const float* boxes = (const float*)d_in[4];
    float* out         = (float*)d_out;

    roi_align_tap8_kernel<<<NROI * 32, 256, 0, stream>>>(f0, f1, f2, f3, boxes, out);
}